// Round 17
// baseline (392.878 us; speedup 1.0000x reference)
//
#include <hip/hip_runtime.h>

// FNO spectral convolution, truncated separable DFT formulation.
// B=8, H=W=256, C_IN=C_OUT=64, modes 32 x 17 (rows fftshift-centered: k_m = m-16).
//
// ROUND-17 DIAGNOSTIC: k2a/k2b/k2c replicated x8 (bijective block shifts,
// idempotent writes) to (a) expose the largest member in top-5 with honest
// counters, (b) give trio_sum = (dur - 130.5)/7. k1 (radix-2 Goertzel),
// k3 (radix-8), k0 unchanged from r16. Next round de-instruments and acts.
//
// ws layout (floats):
//   twD [64 w'][18 pairs]  : 2304
//   twB [256 h][32 m][2]   : 16384
//   twC [32]               : 32
//   G   [B][H][17][64][2]  : 4456448   (aliased by Z after k2a)
//   T   [B][H][17][64][2]  : 4456448   (aliased by P before k2c)
//   P [4 hq][136 bn][32 m][64 i][2] -> lives in T's slot
//   Z [8 b][17 n][32 m][64 o][2]    -> lives in dead G's slot

#define NB 8
#define NH 256
#define NW 256
#define NC 64
#define NM1 32
#define NM2 17
#define HQ 4
#define K2REP 8

__global__ void k0_tw(float* __restrict__ twD, float* __restrict__ twB,
                      float* __restrict__ twC) {
    const float STEP = 0.02454369260617026f; // 2*pi/256
    int t = blockIdx.x * 256 + threadIdx.x;
    if (t < 64 * 18) {
        int w = t / 18, nn = t % 18;
        if (nn < 17) {
            int ph = (nn * w) & 255;
            float ang = (float)ph * STEP;
            twD[w * 36 + 2 * nn + 0] = cosf(ang);
            twD[w * 36 + 2 * nn + 1] = sinf(ang);
        } else {
            twD[w * 36 + 34] = 0.f;
            twD[w * 36 + 35] = 0.f;
        }
    }
    if (t < 256 * 32) {
        int h = t >> 5, m = t & 31;
        int ph = ((m - 16) * h) & 255;
        float ang = (float)ph * STEP;
        twB[t * 2 + 0] = cosf(ang);
        twB[t * 2 + 1] = sinf(ang);
    }
    if (t < 17) {
        twC[t] = 2.0f * cosf((float)t * STEP);
    }
}

// Chunk fixup + 8th-root rotation (r16 verbatim).
template <int QP1>
__device__ __forceinline__ void k1_fixup(float* s1a, float* s2a,
                                         float* s1b, float* s2b,
                                         const float* cn, const float* sn) {
    const float R = 0.7071067811865476f;
    const float CR[8] = {1.f,  R, 0.f, -R, -1.f, -R, 0.f,  R};
    const float SI[8] = {0.f, -R, -1.f, -R, 0.f,  R, 1.f,  R};
    #pragma unroll
    for (int n = 0; n < 17; ++n) {
        float qr0 = fmaf(cn[n], s1a[n], -s2a[n]);
        float qi0 = sn[n] * s1a[n];
        float qr1 = fmaf(cn[n], s1b[n], -s2b[n]);
        float qi1 = sn[n] * s1b[n];
        const int k = (n * QP1) & 7;
        float cr = CR[k], si = SI[k];
        s1a[n] = qr0 * cr - qi0 * si;
        s2a[n] = qr0 * si + qi0 * cr;
        s1b[n] = qr1 * cr - qi1 * si;
        s2b[n] = qr1 * si + qi1 * cr;
    }
}

// K1 (radix-2-folded real Goertzel, r16 verbatim).
__global__ __launch_bounds__(256) void k1_fwdW(const float* __restrict__ x,
                                               const float* __restrict__ twD,
                                               const float* __restrict__ twC,
                                               float* __restrict__ G) {
    __shared__ float lre[4][17][64];
    __shared__ float lim[4][17][64];
    const int tid = threadIdx.x;
    const int i = tid & 63;
    const int wq_u = __builtin_amdgcn_readfirstlane(tid >> 6);
    const int bh0 = blockIdx.x * 2;

    float twoc[17], cn[17], sn[17];
    #pragma unroll
    for (int n = 0; n < 17; ++n) {
        twoc[n] = twC[n];
        cn[n] = twD[36 + 2 * n];
        sn[n] = twD[36 + 2 * n + 1];
    }

    float s1a[17], s2a[17], s1b[17], s2b[17];
    #pragma unroll
    for (int n = 0; n < 17; ++n) { s1a[n]=0.f; s2a[n]=0.f; s1b[n]=0.f; s2b[n]=0.f; }

    const float* xb0  = x + (size_t)bh0 * (NW * NC) + (size_t)wq_u * 32 * 64 + i;
    const float* xb0c = xb0 + 128 * 64;
    const float* xb1  = xb0 + NW * NC;
    const float* xb1c = xb1 + 128 * 64;
    #pragma unroll 2
    for (int j = 0; j < 32; j += 2) {
        float a0 = xb0 [(size_t)j * 64];
        float a1 = xb0 [(size_t)(j + 1) * 64];
        float c0 = xb0c[(size_t)j * 64];
        float c1 = xb0c[(size_t)(j + 1) * 64];
        float b0 = xb1 [(size_t)j * 64];
        float b1 = xb1 [(size_t)(j + 1) * 64];
        float d0 = xb1c[(size_t)j * 64];
        float d1 = xb1c[(size_t)(j + 1) * 64];
        float u0j = a0 + c0, u0k = a1 + c1;
        float v0j = a0 - c0, v0k = a1 - c1;
        float u1j = b0 + d0, u1k = b1 + d1;
        float v1j = b0 - d0, v1k = b1 - d1;
        #pragma unroll
        for (int n = 0; n < 17; ++n) {
            float in0j = (n & 1) ? v0j : u0j;
            float in0k = (n & 1) ? v0k : u0k;
            float in1j = (n & 1) ? v1j : u1j;
            float in1k = (n & 1) ? v1k : u1k;
            float ta = fmaf(twoc[n], s1a[n], in0j) - s2a[n];
            float tb = fmaf(twoc[n], ta, in0k) - s1a[n];
            s2a[n] = ta; s1a[n] = tb;
            float ua = fmaf(twoc[n], s1b[n], in1j) - s2b[n];
            float ub = fmaf(twoc[n], ua, in1k) - s1b[n];
            s2b[n] = ua; s1b[n] = ub;
        }
    }

    switch (wq_u) {
        case 0:  k1_fixup<1>(s1a, s2a, s1b, s2b, cn, sn); break;
        case 1:  k1_fixup<2>(s1a, s2a, s1b, s2b, cn, sn); break;
        case 2:  k1_fixup<3>(s1a, s2a, s1b, s2b, cn, sn); break;
        default: k1_fixup<4>(s1a, s2a, s1b, s2b, cn, sn); break;
    }

    #pragma unroll
    for (int n = 0; n < 17; ++n) { lre[wq_u][n][i] = s1a[n]; lim[wq_u][n][i] = s2a[n]; }
    __syncthreads();
    float2* G0 = (float2*)G + (size_t)bh0 * 17 * 64;
    for (int n = wq_u; n < 17; n += 4) {
        float re = (lre[0][n][i] + lre[1][n][i]) + (lre[2][n][i] + lre[3][n][i]);
        float im = (lim[0][n][i] + lim[1][n][i]) + (lim[2][n][i] + lim[3][n][i]);
        G0[n * 64 + i] = make_float2(re, im);
    }
    __syncthreads();
    #pragma unroll
    for (int n = 0; n < 17; ++n) { lre[wq_u][n][i] = s1b[n]; lim[wq_u][n][i] = s2b[n]; }
    __syncthreads();
    float2* G1 = G0 + 17 * 64;
    for (int n = wq_u; n < 17; n += 4) {
        float re = (lre[0][n][i] + lre[1][n][i]) + (lre[2][n][i] + lre[3][n][i]);
        float im = (lim[0][n][i] + lim[1][n][i]) + (lim[2][n][i] + lim[3][n][i]);
        G1[n * 64 + i] = make_float2(re, im);
    }
}

// K2a: partial H-DFT -- K2REP=8 diagnostic (bijective bn shift, 37 coprime 136).
__global__ __launch_bounds__(256) void k2a_hdft(const float* __restrict__ G,
                                                const float* __restrict__ twB,
                                                float* __restrict__ P) {
    const int hq = blockIdx.y;
    const int t = threadIdx.x;
    const int lane = t & 63;
    const int q_u = __builtin_amdgcn_readfirstlane(t >> 6);

    #pragma unroll 1
    for (int rep = 0; rep < K2REP; ++rep) {
        const int bn = (blockIdx.x + rep * 37) % 136;
        const int b = bn / 17, n = bn % 17;

        float ar[8], ai[8];
        #pragma unroll
        for (int j = 0; j < 8; ++j) { ar[j] = 0.f; ai[j] = 0.f; }

        const float2* Gb = (const float2*)G + ((size_t)b * 256 * 17 + n) * 64 + lane;
        #pragma unroll 2
        for (int hh = 0; hh < 64; ++hh) {
            int h = hq * 64 + hh;
            float2 g = Gb[(size_t)h * (17 * 64)];
            const float* tw = twB + (h * 32 + q_u * 8) * 2;
            #pragma unroll
            for (int j = 0; j < 8; ++j) {
                float c = tw[2 * j], s = tw[2 * j + 1];
                ar[j] = fmaf(g.x, c, fmaf(g.y, s, ar[j]));
                ai[j] = fmaf(g.y, c, fmaf(-g.x, s, ai[j]));
            }
        }
        float2* Pp = (float2*)P + (((size_t)hq * 136 + bn) * 32 + q_u * 8) * 64 + lane;
        #pragma unroll
        for (int j = 0; j < 8; ++j) Pp[j * 64] = make_float2(ar[j], ai[j]);
    }
}

// K2b: mode mix -- K2REP=8 diagnostic (bijective mn shift, 71 coprime 544).
__global__ __launch_bounds__(512) void k2b_mix(const float* __restrict__ P,
                                               const float* __restrict__ Wr,
                                               const float* __restrict__ Wi,
                                               float* __restrict__ Z) {
    __shared__ float2 xs[8 * 64]; // [b][i]
    const int t = threadIdx.x;
    const int lane = t & 63;
    const int q_u = __builtin_amdgcn_readfirstlane(t >> 6);

    #pragma unroll 1
    for (int rep = 0; rep < K2REP; ++rep) {
        const int mn = (blockIdx.x + rep * 71) % 544;
        const int m = mn & 31, n = mn >> 5;

        {
            int b = t >> 6, i = t & 63;
            const float2* Pp = (const float2*)P + (((size_t)(b * 17 + n)) * 32 + m) * 64 + i;
            float re = 0.f, im = 0.f;
            #pragma unroll
            for (int hq = 0; hq < HQ; ++hq) {
                float2 pv = Pp[(size_t)hq * (136 * 32 * 64)];
                re += pv.x; im += pv.y;
            }
            xs[t] = make_float2(re, im);
        }
        __syncthreads();

        const float scale = (n == 0 ? 1.0f : 2.0f) * (1.0f / 65536.0f);
        float zr = 0.f, zi = 0.f;
        const float* Wrp = Wr + (((size_t)m * 17 + n) * 64) * 64 + lane;
        const float* Wip = Wi + (((size_t)m * 17 + n) * 64) * 64 + lane;
        #pragma unroll 4
        for (int i = 0; i < 64; ++i) {
            float wr = Wrp[(size_t)i * 64], wi = Wip[(size_t)i * 64];
            float2 xv = xs[q_u * 64 + i];
            zr = fmaf(xv.x, wr, fmaf(-xv.y, wi, zr));
            zi = fmaf(xv.x, wi, fmaf(xv.y, wr, zi));
        }
        float2* Zp = (float2*)Z;
        Zp[(((size_t)q_u * 17 + n) * 32 + m) * 64 + lane] = make_float2(zr * scale, zi * scale);
        __syncthreads();   // xs reused next rep
    }
}

// K2c: inverse H-DFT -- K2REP=8 diagnostic (bijective bn shift).
__global__ __launch_bounds__(256) void k2c_ihdft(const float* __restrict__ Z,
                                                 const float* __restrict__ twB,
                                                 float* __restrict__ T) {
    __shared__ float2 zs[32 * 64];
    const int hq = blockIdx.y;
    const int t = threadIdx.x;
    const int lane = t & 63;
    const int q_u = __builtin_amdgcn_readfirstlane(t >> 6);

    #pragma unroll 1
    for (int rep = 0; rep < K2REP; ++rep) {
        const int bn = (blockIdx.x + rep * 37) % 136;
        const int b = bn / 17, n = bn % 17;

        const float2* Zp = (const float2*)Z + (((size_t)b * 17 + n) * 32) * 64;
        #pragma unroll
        for (int r = 0; r < 8; ++r) zs[r * 256 + t] = Zp[r * 256 + t];
        __syncthreads();

        float2* Tb = (float2*)T + ((size_t)b * 256 * 17 + n) * 64 + lane;
        #pragma unroll 2
        for (int jj = 0; jj < 8; ++jj) {
            int h = hq * 32 + q_u * 8 + jj;
            const float* tw = twB + h * 64;
            float re0 = 0, im0 = 0, re1 = 0, im1 = 0;
            #pragma unroll
            for (int m = 0; m < 32; m += 2) {
                float2 z0 = zs[m * 64 + lane];
                float c0 = tw[2 * m + 0], s0 = tw[2 * m + 1];
                re0 = fmaf(z0.x, c0, fmaf(-z0.y, s0, re0));
                im0 = fmaf(z0.x, s0, fmaf(z0.y, c0, im0));
                float2 z1 = zs[(m + 1) * 64 + lane];
                float c1 = tw[2 * m + 2], s1 = tw[2 * m + 3];
                re1 = fmaf(z1.x, c1, fmaf(-z1.y, s1, re1));
                im1 = fmaf(z1.x, s1, fmaf(z1.y, c1, im1));
            }
            Tb[(size_t)h * (17 * 64)] = make_float2(re0 + re1, im0 + im1);
        }
        __syncthreads();   // zs reused next rep
    }
}

// K3 (radix-8 fold + LDS-broadcast twiddles, r15/r16 verbatim).
__global__ __launch_bounds__(256) void k3_invW(const float* __restrict__ T,
                                               const float* __restrict__ twD,
                                               float* __restrict__ y) {
    __shared__ float tws[32 * 36];
    const int tid = threadIdx.x;
    const int o = tid & 63;
    const int q_u = __builtin_amdgcn_readfirstlane(tid >> 6);
    const int bh0 = blockIdx.x * 2;
    const float R8 = 0.7071067811865476f;

    {
        const float4* src = (const float4*)twD;
        float4* dst = (float4*)tws;
        #pragma unroll
        for (int v = tid; v < 288; v += 256) dst[v] = src[v];
    }

    const float2* T0 = (const float2*)T + (size_t)bh0 * 17 * 64;
    const float2* T1 = T0 + 17 * 64;
    float tr0[17], ti0[17], tr1[17], ti1[17];
    #pragma unroll
    for (int n = 0; n < 17; ++n) {
        float2 v0 = T0[n * 64 + o];
        tr0[n] = v0.x; ti0[n] = v0.y;
        float2 v1 = T1[n * 64 + o];
        tr1[n] = v1.x; ti1[n] = v1.y;
    }
    __syncthreads();

    float* yb0 = y + (size_t)bh0 * (NW * NC) + o;
    float* yb1 = yb0 + NW * NC;
    #pragma unroll 1
    for (int it = 0; it < 8; ++it) {
        const int wp = q_u * 8 + it;
        const float* tw = &tws[wp * 36];
        float P0a=0,P1a=0,P2a=0,P3a=0,P4a=0,P5a=0,P6a=0,P7a=0;
        float Q1a=0,Q2a=0,Q3a=0,Q5a=0,Q6a=0,Q7a=0;
        float P0b=0,P1b=0,P2b=0,P3b=0,P4b=0,P5b=0,P6b=0,P7b=0;
        float Q1b=0,Q2b=0,Q3b=0,Q5b=0,Q6b=0,Q7b=0;

        #pragma unroll
        for (int n = 0; n < 17; n += 8) {
            float c = tw[2*n], s = tw[2*n+1];
            P0a = fmaf(tr0[n], c, fmaf(-ti0[n], s, P0a));
            P0b = fmaf(tr1[n], c, fmaf(-ti1[n], s, P0b));
        }
        #pragma unroll
        for (int n = 4; n < 17; n += 8) {
            float c = tw[2*n], s = tw[2*n+1];
            P4a = fmaf(tr0[n], c, fmaf(-ti0[n], s, P4a));
            P4b = fmaf(tr1[n], c, fmaf(-ti1[n], s, P4b));
        }
        #pragma unroll
        for (int n = 1; n < 17; n += 8) {
            float c = tw[2*n], s = tw[2*n+1];
            P1a = fmaf(tr0[n], c, fmaf(-ti0[n], s, P1a));
            Q1a = fmaf(tr0[n], s, fmaf( ti0[n], c, Q1a));
            P1b = fmaf(tr1[n], c, fmaf(-ti1[n], s, P1b));
            Q1b = fmaf(tr1[n], s, fmaf( ti1[n], c, Q1b));
        }
        #pragma unroll
        for (int n = 2; n < 17; n += 8) {
            float c = tw[2*n], s = tw[2*n+1];
            P2a = fmaf(tr0[n], c, fmaf(-ti0[n], s, P2a));
            Q2a = fmaf(tr0[n], s, fmaf( ti0[n], c, Q2a));
            P2b = fmaf(tr1[n], c, fmaf(-ti1[n], s, P2b));
            Q2b = fmaf(tr1[n], s, fmaf( ti1[n], c, Q2b));
        }
        #pragma unroll
        for (int n = 3; n < 17; n += 8) {
            float c = tw[2*n], s = tw[2*n+1];
            P3a = fmaf(tr0[n], c, fmaf(-ti0[n], s, P3a));
            Q3a = fmaf(tr0[n], s, fmaf( ti0[n], c, Q3a));
            P3b = fmaf(tr1[n], c, fmaf(-ti1[n], s, P3b));
            Q3b = fmaf(tr1[n], s, fmaf( ti1[n], c, Q3b));
        }
        #pragma unroll
        for (int n = 5; n < 17; n += 8) {
            float c = tw[2*n], s = tw[2*n+1];
            P5a = fmaf(tr0[n], c, fmaf(-ti0[n], s, P5a));
            Q5a = fmaf(tr0[n], s, fmaf( ti0[n], c, Q5a));
            P5b = fmaf(tr1[n], c, fmaf(-ti1[n], s, P5b));
            Q5b = fmaf(tr1[n], s, fmaf( ti1[n], c, Q5b));
        }
        #pragma unroll
        for (int n = 6; n < 17; n += 8) {
            float c = tw[2*n], s = tw[2*n+1];
            P6a = fmaf(tr0[n], c, fmaf(-ti0[n], s, P6a));
            Q6a = fmaf(tr0[n], s, fmaf( ti0[n], c, Q6a));
            P6b = fmaf(tr1[n], c, fmaf(-ti1[n], s, P6b));
            Q6b = fmaf(tr1[n], s, fmaf( ti1[n], c, Q6b));
        }
        #pragma unroll
        for (int n = 7; n < 17; n += 8) {
            float c = tw[2*n], s = tw[2*n+1];
            P7a = fmaf(tr0[n], c, fmaf(-ti0[n], s, P7a));
            Q7a = fmaf(tr0[n], s, fmaf( ti0[n], c, Q7a));
            P7b = fmaf(tr1[n], c, fmaf(-ti1[n], s, P7b));
            Q7b = fmaf(tr1[n], s, fmaf( ti1[n], c, Q7b));
        }

        {
            float Se = (P0a + P2a) + (P4a + P6a);
            float So = (P1a + P3a) + (P5a + P7a);
            float C  = (P0a - P2a) + (P4a - P6a);
            float S  = (Q3a - Q1a) + (Q7a - Q5a);
            float D  = P0a - P4a;
            float Hq = Q2a - Q6a;
            float G1 = (P1a - P3a) - (P5a - P7a);
            float G2 = (Q1a + Q3a) - (Q5a + Q7a);
            float u  = R8 * (G1 - G2);
            float v  = R8 * (G1 + G2);
            float dm = D - Hq, dp = D + Hq;
            yb0[(size_t)(wp +   0) * 64] = Se + So;
            yb0[(size_t)(wp +  32) * 64] = dm + u;
            yb0[(size_t)(wp +  64) * 64] = C + S;
            yb0[(size_t)(wp +  96) * 64] = dp - v;
            yb0[(size_t)(wp + 128) * 64] = Se - So;
            yb0[(size_t)(wp + 160) * 64] = dm - u;
            yb0[(size_t)(wp + 192) * 64] = C - S;
            yb0[(size_t)(wp + 224) * 64] = dp + v;
        }
        {
            float Se = (P0b + P2b) + (P4b + P6b);
            float So = (P1b + P3b) + (P5b + P7b);
            float C  = (P0b - P2b) + (P4b - P6b);
            float S  = (Q3b - Q1b) + (Q7b - Q5b);
            float D  = P0b - P4b;
            float Hq = Q2b - Q6b;
            float G1 = (P1b - P3b) - (P5b - P7b);
            float G2 = (Q1b + Q3b) - (Q5b + Q7b);
            float u  = R8 * (G1 - G2);
            float v  = R8 * (G1 + G2);
            float dm = D - Hq, dp = D + Hq;
            yb1[(size_t)(wp +   0) * 64] = Se + So;
            yb1[(size_t)(wp +  32) * 64] = dm + u;
            yb1[(size_t)(wp +  64) * 64] = C + S;
            yb1[(size_t)(wp +  96) * 64] = dp - v;
            yb1[(size_t)(wp + 128) * 64] = Se - So;
            yb1[(size_t)(wp + 160) * 64] = dm - u;
            yb1[(size_t)(wp + 192) * 64] = C - S;
            yb1[(size_t)(wp + 224) * 64] = dp + v;
        }
    }
}

extern "C" void kernel_launch(void* const* d_in, const int* in_sizes, int n_in,
                              void* d_out, int out_size, void* d_ws, size_t ws_size,
                              hipStream_t stream) {
    (void)in_sizes; (void)n_in; (void)out_size; (void)ws_size;
    const float* x  = (const float*)d_in[0];
    const float* Wr = (const float*)d_in[1];
    const float* Wi = (const float*)d_in[2];
    float* out = (float*)d_out;
    float* ws  = (float*)d_ws;

    float* twD = ws;                 // 2304 floats
    float* twB = ws + 2304;          // 16384 floats
    float* twC = ws + 18688;         // 32 floats
    float* G   = ws + 18720;         // 4456448 floats
    float* T   = G + 4456448;        // 4456448 floats
    float* P   = T;                  // alias
    float* Z   = G;                  // alias

    k0_tw<<<32, 256, 0, stream>>>(twD, twB, twC);
    k1_fwdW<<<NB * NH / 2, 256, 0, stream>>>(x, twD, twC, G);
    k2a_hdft<<<dim3(NB * NM2, HQ), 256, 0, stream>>>(G, twB, P);
    k2b_mix<<<NM1 * NM2, 512, 0, stream>>>(P, Wr, Wi, Z);
    k2c_ihdft<<<dim3(NB * NM2, 8), 256, 0, stream>>>(Z, twB, T);
    k3_invW<<<NB * NH / 2, 256, 0, stream>>>(T, twD, out);
}

// Round 18
// 115.979 us; speedup vs baseline: 3.3875x; 3.3875x over previous
//
#include <hip/hip_runtime.h>

// FNO spectral convolution, truncated separable DFT formulation.
// B=8, H=W=256, C_IN=C_OUT=64, modes 32 x 17 (rows fftshift-centered: k_m = m-16).
//
// Round-18 (anchor r16 = 130.5; r17 diag: k2c = 20.8us/rep, VALUBusy 50%,
// Occ 18% -- LDS/SMEM issue-bound like pre-radix k3): ONE change -- k2c
// radix-4 h-fold. cis(2pi(m-16)(h'+64j)/256) = cis(2pi(m-16)h'/256) * i^{mj}
// => per-class A_k (k = m mod 4), T(h'+64j) = sum_k i^{jk} A_k. Per h' the
// same 32 zs-reads + 32 tw-pairs + 128 fma now yield 4 outputs (was 1).
// k0/k1/k2a/k2b/k3 verbatim from r16 (k2a/k2b de-instrumented to 1 rep).
//
// ws layout (floats):
//   twD [64 w'][18 pairs]  : 2304
//   twB [256 h][32 m][2]   : 16384   (k2c uses rows 0..63 only now)
//   twC [32]               : 32
//   G   [B][H][17][64][2]  : 4456448   (aliased by Z after k2a)
//   T   [B][H][17][64][2]  : 4456448   (aliased by P before k2c)
//   P [4 hq][136 bn][32 m][64 i][2] -> lives in T's slot
//   Z [8 b][17 n][32 m][64 o][2]    -> lives in dead G's slot

#define NB 8
#define NH 256
#define NW 256
#define NC 64
#define NM1 32
#define NM2 17
#define HQ 4

__global__ void k0_tw(float* __restrict__ twD, float* __restrict__ twB,
                      float* __restrict__ twC) {
    const float STEP = 0.02454369260617026f; // 2*pi/256
    int t = blockIdx.x * 256 + threadIdx.x;
    if (t < 64 * 18) {
        int w = t / 18, nn = t % 18;
        if (nn < 17) {
            int ph = (nn * w) & 255;
            float ang = (float)ph * STEP;
            twD[w * 36 + 2 * nn + 0] = cosf(ang);
            twD[w * 36 + 2 * nn + 1] = sinf(ang);
        } else {
            twD[w * 36 + 34] = 0.f;
            twD[w * 36 + 35] = 0.f;
        }
    }
    if (t < 256 * 32) {
        int h = t >> 5, m = t & 31;
        int ph = ((m - 16) * h) & 255; // two's complement & 255 == mod 256
        float ang = (float)ph * STEP;
        twB[t * 2 + 0] = cosf(ang);
        twB[t * 2 + 1] = sinf(ang);
    }
    if (t < 17) {
        twC[t] = 2.0f * cosf((float)t * STEP);
    }
}

// Chunk fixup + 8th-root rotation (r16 verbatim).
template <int QP1>
__device__ __forceinline__ void k1_fixup(float* s1a, float* s2a,
                                         float* s1b, float* s2b,
                                         const float* cn, const float* sn) {
    const float R = 0.7071067811865476f;
    const float CR[8] = {1.f,  R, 0.f, -R, -1.f, -R, 0.f,  R};
    const float SI[8] = {0.f, -R, -1.f, -R, 0.f,  R, 1.f,  R};
    #pragma unroll
    for (int n = 0; n < 17; ++n) {
        float qr0 = fmaf(cn[n], s1a[n], -s2a[n]);
        float qi0 = sn[n] * s1a[n];
        float qr1 = fmaf(cn[n], s1b[n], -s2b[n]);
        float qi1 = sn[n] * s1b[n];
        const int k = (n * QP1) & 7;
        float cr = CR[k], si = SI[k];
        s1a[n] = qr0 * cr - qi0 * si;
        s2a[n] = qr0 * si + qi0 * cr;
        s1b[n] = qr1 * cr - qi1 * si;
        s2b[n] = qr1 * si + qi1 * cr;
    }
}

// K1 (radix-2-folded real Goertzel, r16 verbatim).
__global__ __launch_bounds__(256) void k1_fwdW(const float* __restrict__ x,
                                               const float* __restrict__ twD,
                                               const float* __restrict__ twC,
                                               float* __restrict__ G) {
    __shared__ float lre[4][17][64];
    __shared__ float lim[4][17][64];
    const int tid = threadIdx.x;
    const int i = tid & 63;
    const int wq_u = __builtin_amdgcn_readfirstlane(tid >> 6);
    const int bh0 = blockIdx.x * 2;

    float twoc[17], cn[17], sn[17];
    #pragma unroll
    for (int n = 0; n < 17; ++n) {
        twoc[n] = twC[n];
        cn[n] = twD[36 + 2 * n];
        sn[n] = twD[36 + 2 * n + 1];
    }

    float s1a[17], s2a[17], s1b[17], s2b[17];
    #pragma unroll
    for (int n = 0; n < 17; ++n) { s1a[n]=0.f; s2a[n]=0.f; s1b[n]=0.f; s2b[n]=0.f; }

    const float* xb0  = x + (size_t)bh0 * (NW * NC) + (size_t)wq_u * 32 * 64 + i;
    const float* xb0c = xb0 + 128 * 64;
    const float* xb1  = xb0 + NW * NC;
    const float* xb1c = xb1 + 128 * 64;
    #pragma unroll 2
    for (int j = 0; j < 32; j += 2) {
        float a0 = xb0 [(size_t)j * 64];
        float a1 = xb0 [(size_t)(j + 1) * 64];
        float c0 = xb0c[(size_t)j * 64];
        float c1 = xb0c[(size_t)(j + 1) * 64];
        float b0 = xb1 [(size_t)j * 64];
        float b1 = xb1 [(size_t)(j + 1) * 64];
        float d0 = xb1c[(size_t)j * 64];
        float d1 = xb1c[(size_t)(j + 1) * 64];
        float u0j = a0 + c0, u0k = a1 + c1;
        float v0j = a0 - c0, v0k = a1 - c1;
        float u1j = b0 + d0, u1k = b1 + d1;
        float v1j = b0 - d0, v1k = b1 - d1;
        #pragma unroll
        for (int n = 0; n < 17; ++n) {
            float in0j = (n & 1) ? v0j : u0j;
            float in0k = (n & 1) ? v0k : u0k;
            float in1j = (n & 1) ? v1j : u1j;
            float in1k = (n & 1) ? v1k : u1k;
            float ta = fmaf(twoc[n], s1a[n], in0j) - s2a[n];
            float tb = fmaf(twoc[n], ta, in0k) - s1a[n];
            s2a[n] = ta; s1a[n] = tb;
            float ua = fmaf(twoc[n], s1b[n], in1j) - s2b[n];
            float ub = fmaf(twoc[n], ua, in1k) - s1b[n];
            s2b[n] = ua; s1b[n] = ub;
        }
    }

    switch (wq_u) {
        case 0:  k1_fixup<1>(s1a, s2a, s1b, s2b, cn, sn); break;
        case 1:  k1_fixup<2>(s1a, s2a, s1b, s2b, cn, sn); break;
        case 2:  k1_fixup<3>(s1a, s2a, s1b, s2b, cn, sn); break;
        default: k1_fixup<4>(s1a, s2a, s1b, s2b, cn, sn); break;
    }

    #pragma unroll
    for (int n = 0; n < 17; ++n) { lre[wq_u][n][i] = s1a[n]; lim[wq_u][n][i] = s2a[n]; }
    __syncthreads();
    float2* G0 = (float2*)G + (size_t)bh0 * 17 * 64;
    for (int n = wq_u; n < 17; n += 4) {
        float re = (lre[0][n][i] + lre[1][n][i]) + (lre[2][n][i] + lre[3][n][i]);
        float im = (lim[0][n][i] + lim[1][n][i]) + (lim[2][n][i] + lim[3][n][i]);
        G0[n * 64 + i] = make_float2(re, im);
    }
    __syncthreads();
    #pragma unroll
    for (int n = 0; n < 17; ++n) { lre[wq_u][n][i] = s1b[n]; lim[wq_u][n][i] = s2b[n]; }
    __syncthreads();
    float2* G1 = G0 + 17 * 64;
    for (int n = wq_u; n < 17; n += 4) {
        float re = (lre[0][n][i] + lre[1][n][i]) + (lre[2][n][i] + lre[3][n][i]);
        float im = (lim[0][n][i] + lim[1][n][i]) + (lim[2][n][i] + lim[3][n][i]);
        G1[n * 64 + i] = make_float2(re, im);
    }
}

// K2a: partial H-DFT. grid (136 bn, 4 hq). (r16 verbatim, single rep)
__global__ __launch_bounds__(256) void k2a_hdft(const float* __restrict__ G,
                                                const float* __restrict__ twB,
                                                float* __restrict__ P) {
    const int bn = blockIdx.x;
    const int b = bn / 17, n = bn % 17;
    const int hq = blockIdx.y;
    const int t = threadIdx.x;
    const int lane = t & 63;
    const int q_u = __builtin_amdgcn_readfirstlane(t >> 6);

    float ar[8], ai[8];
    #pragma unroll
    for (int j = 0; j < 8; ++j) { ar[j] = 0.f; ai[j] = 0.f; }

    const float2* Gb = (const float2*)G + ((size_t)b * 256 * 17 + n) * 64 + lane;
    #pragma unroll 2
    for (int hh = 0; hh < 64; ++hh) {
        int h = hq * 64 + hh;
        float2 g = Gb[(size_t)h * (17 * 64)];
        const float* tw = twB + (h * 32 + q_u * 8) * 2;
        #pragma unroll
        for (int j = 0; j < 8; ++j) {
            float c = tw[2 * j], s = tw[2 * j + 1];
            ar[j] = fmaf(g.x, c, fmaf(g.y, s, ar[j]));
            ai[j] = fmaf(g.y, c, fmaf(-g.x, s, ai[j]));
        }
    }
    float2* Pp = (float2*)P + (((size_t)hq * 136 + bn) * 32 + q_u * 8) * 64 + lane;
    #pragma unroll
    for (int j = 0; j < 8; ++j) Pp[j * 64] = make_float2(ar[j], ai[j]);
}

// K2b: 512 threads, wave-per-b. (r16 verbatim, single rep)
__global__ __launch_bounds__(512) void k2b_mix(const float* __restrict__ P,
                                               const float* __restrict__ Wr,
                                               const float* __restrict__ Wi,
                                               float* __restrict__ Z) {
    __shared__ float2 xs[8 * 64]; // [b][i]
    const int mn = blockIdx.x;
    const int m = mn & 31, n = mn >> 5;
    const int t = threadIdx.x;
    const int lane = t & 63;
    const int q_u = __builtin_amdgcn_readfirstlane(t >> 6); // b for this wave

    {
        int b = t >> 6, i = t & 63;
        const float2* Pp = (const float2*)P + (((size_t)(b * 17 + n)) * 32 + m) * 64 + i;
        float re = 0.f, im = 0.f;
        #pragma unroll
        for (int hq = 0; hq < HQ; ++hq) {
            float2 pv = Pp[(size_t)hq * (136 * 32 * 64)];
            re += pv.x; im += pv.y;
        }
        xs[t] = make_float2(re, im);
    }
    __syncthreads();

    const float scale = (n == 0 ? 1.0f : 2.0f) * (1.0f / 65536.0f);
    float zr = 0.f, zi = 0.f;
    const float* Wrp = Wr + (((size_t)m * 17 + n) * 64) * 64 + lane;
    const float* Wip = Wi + (((size_t)m * 17 + n) * 64) * 64 + lane;
    #pragma unroll 4
    for (int i = 0; i < 64; ++i) {
        float wr = Wrp[(size_t)i * 64], wi = Wip[(size_t)i * 64];
        float2 xv = xs[q_u * 64 + i];  // wave-uniform -> LDS broadcast
        zr = fmaf(xv.x, wr, fmaf(-xv.y, wi, zr));
        zi = fmaf(xv.x, wi, fmaf(xv.y, wr, zi));
    }
    float2* Zp = (float2*)Z;
    Zp[(((size_t)q_u * 17 + n) * 32 + m) * 64 + lane] = make_float2(zr * scale, zi * scale);
}

// K2c (radix-4 h-fold): T[b, h'+64j, n, o] = sum_k i^{jk} A_k,
// A_k = sum_{m == k mod 4} Z[m,o] cis(+2pi(m-16)h'/256), h' in [0,64).
// grid (136, 8): block handles 8 h', wave q handles 2. Per h': 32 zs b64
// reads + 16 tw b128 broadcasts + 128 fma -> FOUR complex outputs (was 1).
// Epilogue: E,F = A0+-A2; G,H = A1+-A3; j0=E+G, j1=F+iH, j2=E-G, j3=F-iH.
__global__ __launch_bounds__(256) void k2c_ihdft(const float* __restrict__ Z,
                                                 const float* __restrict__ twB,
                                                 float* __restrict__ T) {
    __shared__ float2 zs[32 * 64];  // 16 KB
    __shared__ float tws[8 * 64];   // 2 KB: twB rows h' = hq*8 .. hq*8+8
    const int bn = blockIdx.x;
    const int b = bn / 17, n = bn % 17;
    const int hq = blockIdx.y;      // 0..7
    const int t = threadIdx.x;
    const int lane = t & 63;
    const int q_u = __builtin_amdgcn_readfirstlane(t >> 6);

    const float2* Zp = (const float2*)Z + (((size_t)b * 17 + n) * 32) * 64;
    #pragma unroll
    for (int r = 0; r < 8; ++r) zs[r * 256 + t] = Zp[r * 256 + t];
    if (t < 128) {
        ((float4*)tws)[t] = ((const float4*)(twB + (size_t)hq * 8 * 64))[t];
    }
    __syncthreads();

    float2* Tb = (float2*)T + ((size_t)b * 256 * 17 + n) * 64 + lane;
    #pragma unroll
    for (int jj = 0; jj < 2; ++jj) {
        const int hl = q_u * 2 + jj;            // local row 0..7
        const int hp = hq * 8 + hl;             // h' in [0,64)
        const float* tw = &tws[hl * 64];        // wave-uniform -> broadcast
        float A0r=0,A0i=0,A1r=0,A1i=0,A2r=0,A2i=0,A3r=0,A3i=0;
        #pragma unroll
        for (int m = 0; m < 32; m += 4) {
            float2 z0 = zs[(m + 0) * 64 + lane];
            float c0 = tw[2*m + 0], s0 = tw[2*m + 1];
            A0r = fmaf(z0.x, c0, fmaf(-z0.y, s0, A0r));
            A0i = fmaf(z0.x, s0, fmaf( z0.y, c0, A0i));
            float2 z1 = zs[(m + 1) * 64 + lane];
            float c1 = tw[2*m + 2], s1 = tw[2*m + 3];
            A1r = fmaf(z1.x, c1, fmaf(-z1.y, s1, A1r));
            A1i = fmaf(z1.x, s1, fmaf( z1.y, c1, A1i));
            float2 z2 = zs[(m + 2) * 64 + lane];
            float c2 = tw[2*m + 4], s2 = tw[2*m + 5];
            A2r = fmaf(z2.x, c2, fmaf(-z2.y, s2, A2r));
            A2i = fmaf(z2.x, s2, fmaf( z2.y, c2, A2i));
            float2 z3 = zs[(m + 3) * 64 + lane];
            float c3 = tw[2*m + 6], s3 = tw[2*m + 7];
            A3r = fmaf(z3.x, c3, fmaf(-z3.y, s3, A3r));
            A3i = fmaf(z3.x, s3, fmaf( z3.y, c3, A3i));
        }
        float Er = A0r + A2r, Ei = A0i + A2i;
        float Fr = A0r - A2r, Fi = A0i - A2i;
        float Gr = A1r + A3r, Gi = A1i + A3i;
        float Hr = A1r - A3r, Hi = A1i - A3i;
        Tb[(size_t)(hp +   0) * (17 * 64)] = make_float2(Er + Gr, Ei + Gi); // j=0
        Tb[(size_t)(hp +  64) * (17 * 64)] = make_float2(Fr - Hi, Fi + Hr); // j=1
        Tb[(size_t)(hp + 128) * (17 * 64)] = make_float2(Er - Gr, Ei - Gi); // j=2
        Tb[(size_t)(hp + 192) * (17 * 64)] = make_float2(Fr + Hi, Fi - Hr); // j=3
    }
}

// K3 (radix-8 fold + LDS-broadcast twiddles, r15/r16 verbatim).
__global__ __launch_bounds__(256) void k3_invW(const float* __restrict__ T,
                                               const float* __restrict__ twD,
                                               float* __restrict__ y) {
    __shared__ float tws[32 * 36];
    const int tid = threadIdx.x;
    const int o = tid & 63;
    const int q_u = __builtin_amdgcn_readfirstlane(tid >> 6);
    const int bh0 = blockIdx.x * 2;
    const float R8 = 0.7071067811865476f;

    {
        const float4* src = (const float4*)twD;
        float4* dst = (float4*)tws;
        #pragma unroll
        for (int v = tid; v < 288; v += 256) dst[v] = src[v];
    }

    const float2* T0 = (const float2*)T + (size_t)bh0 * 17 * 64;
    const float2* T1 = T0 + 17 * 64;
    float tr0[17], ti0[17], tr1[17], ti1[17];
    #pragma unroll
    for (int n = 0; n < 17; ++n) {
        float2 v0 = T0[n * 64 + o];
        tr0[n] = v0.x; ti0[n] = v0.y;
        float2 v1 = T1[n * 64 + o];
        tr1[n] = v1.x; ti1[n] = v1.y;
    }
    __syncthreads();

    float* yb0 = y + (size_t)bh0 * (NW * NC) + o;
    float* yb1 = yb0 + NW * NC;
    #pragma unroll 1
    for (int it = 0; it < 8; ++it) {
        const int wp = q_u * 8 + it;
        const float* tw = &tws[wp * 36];
        float P0a=0,P1a=0,P2a=0,P3a=0,P4a=0,P5a=0,P6a=0,P7a=0;
        float Q1a=0,Q2a=0,Q3a=0,Q5a=0,Q6a=0,Q7a=0;
        float P0b=0,P1b=0,P2b=0,P3b=0,P4b=0,P5b=0,P6b=0,P7b=0;
        float Q1b=0,Q2b=0,Q3b=0,Q5b=0,Q6b=0,Q7b=0;

        #pragma unroll
        for (int n = 0; n < 17; n += 8) {
            float c = tw[2*n], s = tw[2*n+1];
            P0a = fmaf(tr0[n], c, fmaf(-ti0[n], s, P0a));
            P0b = fmaf(tr1[n], c, fmaf(-ti1[n], s, P0b));
        }
        #pragma unroll
        for (int n = 4; n < 17; n += 8) {
            float c = tw[2*n], s = tw[2*n+1];
            P4a = fmaf(tr0[n], c, fmaf(-ti0[n], s, P4a));
            P4b = fmaf(tr1[n], c, fmaf(-ti1[n], s, P4b));
        }
        #pragma unroll
        for (int n = 1; n < 17; n += 8) {
            float c = tw[2*n], s = tw[2*n+1];
            P1a = fmaf(tr0[n], c, fmaf(-ti0[n], s, P1a));
            Q1a = fmaf(tr0[n], s, fmaf( ti0[n], c, Q1a));
            P1b = fmaf(tr1[n], c, fmaf(-ti1[n], s, P1b));
            Q1b = fmaf(tr1[n], s, fmaf( ti1[n], c, Q1b));
        }
        #pragma unroll
        for (int n = 2; n < 17; n += 8) {
            float c = tw[2*n], s = tw[2*n+1];
            P2a = fmaf(tr0[n], c, fmaf(-ti0[n], s, P2a));
            Q2a = fmaf(tr0[n], s, fmaf( ti0[n], c, Q2a));
            P2b = fmaf(tr1[n], c, fmaf(-ti1[n], s, P2b));
            Q2b = fmaf(tr1[n], s, fmaf( ti1[n], c, Q2b));
        }
        #pragma unroll
        for (int n = 3; n < 17; n += 8) {
            float c = tw[2*n], s = tw[2*n+1];
            P3a = fmaf(tr0[n], c, fmaf(-ti0[n], s, P3a));
            Q3a = fmaf(tr0[n], s, fmaf( ti0[n], c, Q3a));
            P3b = fmaf(tr1[n], c, fmaf(-ti1[n], s, P3b));
            Q3b = fmaf(tr1[n], s, fmaf( ti1[n], c, Q3b));
        }
        #pragma unroll
        for (int n = 5; n < 17; n += 8) {
            float c = tw[2*n], s = tw[2*n+1];
            P5a = fmaf(tr0[n], c, fmaf(-ti0[n], s, P5a));
            Q5a = fmaf(tr0[n], s, fmaf( ti0[n], c, Q5a));
            P5b = fmaf(tr1[n], c, fmaf(-ti1[n], s, P5b));
            Q5b = fmaf(tr1[n], s, fmaf( ti1[n], c, Q5b));
        }
        #pragma unroll
        for (int n = 6; n < 17; n += 8) {
            float c = tw[2*n], s = tw[2*n+1];
            P6a = fmaf(tr0[n], c, fmaf(-ti0[n], s, P6a));
            Q6a = fmaf(tr0[n], s, fmaf( ti0[n], c, Q6a));
            P6b = fmaf(tr1[n], c, fmaf(-ti1[n], s, P6b));
            Q6b = fmaf(tr1[n], s, fmaf( ti1[n], c, Q6b));
        }
        #pragma unroll
        for (int n = 7; n < 17; n += 8) {
            float c = tw[2*n], s = tw[2*n+1];
            P7a = fmaf(tr0[n], c, fmaf(-ti0[n], s, P7a));
            Q7a = fmaf(tr0[n], s, fmaf( ti0[n], c, Q7a));
            P7b = fmaf(tr1[n], c, fmaf(-ti1[n], s, P7b));
            Q7b = fmaf(tr1[n], s, fmaf( ti1[n], c, Q7b));
        }

        {
            float Se = (P0a + P2a) + (P4a + P6a);
            float So = (P1a + P3a) + (P5a + P7a);
            float C  = (P0a - P2a) + (P4a - P6a);
            float S  = (Q3a - Q1a) + (Q7a - Q5a);
            float D  = P0a - P4a;
            float Hq = Q2a - Q6a;
            float G1 = (P1a - P3a) - (P5a - P7a);
            float G2 = (Q1a + Q3a) - (Q5a + Q7a);
            float u  = R8 * (G1 - G2);
            float v  = R8 * (G1 + G2);
            float dm = D - Hq, dp = D + Hq;
            yb0[(size_t)(wp +   0) * 64] = Se + So;
            yb0[(size_t)(wp +  32) * 64] = dm + u;
            yb0[(size_t)(wp +  64) * 64] = C + S;
            yb0[(size_t)(wp +  96) * 64] = dp - v;
            yb0[(size_t)(wp + 128) * 64] = Se - So;
            yb0[(size_t)(wp + 160) * 64] = dm - u;
            yb0[(size_t)(wp + 192) * 64] = C - S;
            yb0[(size_t)(wp + 224) * 64] = dp + v;
        }
        {
            float Se = (P0b + P2b) + (P4b + P6b);
            float So = (P1b + P3b) + (P5b + P7b);
            float C  = (P0b - P2b) + (P4b - P6b);
            float S  = (Q3b - Q1b) + (Q7b - Q5b);
            float D  = P0b - P4b;
            float Hq = Q2b - Q6b;
            float G1 = (P1b - P3b) - (P5b - P7b);
            float G2 = (Q1b + Q3b) - (Q5b + Q7b);
            float u  = R8 * (G1 - G2);
            float v  = R8 * (G1 + G2);
            float dm = D - Hq, dp = D + Hq;
            yb1[(size_t)(wp +   0) * 64] = Se + So;
            yb1[(size_t)(wp +  32) * 64] = dm + u;
            yb1[(size_t)(wp +  64) * 64] = C + S;
            yb1[(size_t)(wp +  96) * 64] = dp - v;
            yb1[(size_t)(wp + 128) * 64] = Se - So;
            yb1[(size_t)(wp + 160) * 64] = dm - u;
            yb1[(size_t)(wp + 192) * 64] = C - S;
            yb1[(size_t)(wp + 224) * 64] = dp + v;
        }
    }
}

extern "C" void kernel_launch(void* const* d_in, const int* in_sizes, int n_in,
                              void* d_out, int out_size, void* d_ws, size_t ws_size,
                              hipStream_t stream) {
    (void)in_sizes; (void)n_in; (void)out_size; (void)ws_size;
    const float* x  = (const float*)d_in[0];
    const float* Wr = (const float*)d_in[1];
    const float* Wi = (const float*)d_in[2];
    float* out = (float*)d_out;
    float* ws  = (float*)d_ws;

    float* twD = ws;                 // 2304 floats
    float* twB = ws + 2304;          // 16384 floats
    float* twC = ws + 18688;         // 32 floats
    float* G   = ws + 18720;         // 4456448 floats
    float* T   = G + 4456448;        // 4456448 floats
    float* P   = T;                  // alias: partials live in T's slot
    float* Z   = G;                  // alias: Z lives in dead G's slot

    k0_tw<<<32, 256, 0, stream>>>(twD, twB, twC);
    k1_fwdW<<<NB * NH / 2, 256, 0, stream>>>(x, twD, twC, G);
    k2a_hdft<<<dim3(NB * NM2, HQ), 256, 0, stream>>>(G, twB, P);
    k2b_mix<<<NM1 * NM2, 512, 0, stream>>>(P, Wr, Wi, Z);
    k2c_ihdft<<<dim3(NB * NM2, 8), 256, 0, stream>>>(Z, twB, T);
    k3_invW<<<NB * NH / 2, 256, 0, stream>>>(T, twD, out);
}